// Round 1
// baseline (631.498 us; speedup 1.0000x reference)
//
#include <hip/hip_runtime.h>
#include <hip/hip_bf16.h>

// ---------------- CSR build ----------------

__global__ __launch_bounds__(256) void count_deg(const int* __restrict__ row,
                                                 int* __restrict__ cnt, int e) {
    int i = blockIdx.x * 256 + threadIdx.x;
    if (i < e) atomicAdd(&cnt[row[i]], 1);
}

__global__ __launch_bounds__(1024) void scan1(const int* __restrict__ cnt,
                                              int* __restrict__ off,
                                              int* __restrict__ bsum, int n) {
    __shared__ int s[1024];
    int tid = threadIdx.x;
    int i = blockIdx.x * 1024 + tid;
    int v = (i < n) ? cnt[i] : 0;
    s[tid] = v;
    __syncthreads();
    for (int d = 1; d < 1024; d <<= 1) {
        int t = (tid >= d) ? s[tid - d] : 0;
        __syncthreads();
        if (tid >= d) s[tid] += t;
        __syncthreads();
    }
    if (i < n) off[i + 1] = s[tid];
    if (tid == 1023) bsum[blockIdx.x] = s[1023];
}

__global__ __launch_bounds__(1024) void scan2(int* __restrict__ bsum, int nb) {
    __shared__ int s[1024];
    int tid = threadIdx.x;
    int v = (tid < nb) ? bsum[tid] : 0;
    s[tid] = v;
    __syncthreads();
    for (int d = 1; d < 1024; d <<= 1) {
        int t = (tid >= d) ? s[tid - d] : 0;
        __syncthreads();
        if (tid >= d) s[tid] += t;
        __syncthreads();
    }
    int ex = (tid == 0) ? 0 : s[tid - 1];
    __syncthreads();
    if (tid < nb) bsum[tid] = ex;
}

__global__ __launch_bounds__(256) void scan3(int* __restrict__ off,
                                             const int* __restrict__ bsum, int n) {
    int i = blockIdx.x * 256 + threadIdx.x;
    if (i < n) off[i + 1] += bsum[i >> 10];
    if (i == 0) off[0] = 0;
}

__global__ __launch_bounds__(256) void compute_dis(const int* __restrict__ cnt,
                                                   float* __restrict__ dis, int n) {
    int i = blockIdx.x * 256 + threadIdx.x;
    if (i < n) {
        int c = cnt[i];
        dis[i] = (c > 0) ? rsqrtf((float)c) : 0.0f;
    }
}

__global__ __launch_bounds__(256) void fill_csr(const int* __restrict__ row,
                                                const int* __restrict__ col,
                                                const int* __restrict__ off,
                                                int* __restrict__ cursor,
                                                int* __restrict__ csr, int e) {
    int i = blockIdx.x * 256 + threadIdx.x;
    if (i < e) {
        int r = row[i];
        int p = atomicAdd(&cursor[r], 1);
        csr[off[r] + p] = col[i];
    }
}

// ---------------- y = dis[i] * x[i][:] ----------------

__global__ __launch_bounds__(256) void scale_y(const float* __restrict__ x,
                                               const float* __restrict__ dis,
                                               float* __restrict__ y, int n) {
    int id = blockIdx.x * 256 + threadIdx.x;  // over N*16 float4s
    if (id < n * 16) {
        int r = id >> 4;
        float d = dis[r];
        float4 v = ((const float4*)x)[id];
        float4 o = {v.x * d, v.y * d, v.z * d, v.w * d};
        ((float4*)y)[id] = o;
    }
}

// ---------------- aggregate: tx[r][f] = -dis[r] * sum_e y[col][f] ----------------

__global__ __launch_bounds__(256) void aggregate(const float* __restrict__ y,
                                                 const int* __restrict__ csr,
                                                 const int* __restrict__ off,
                                                 const float* __restrict__ dis,
                                                 float* __restrict__ tx, int n) {
    int r = blockIdx.x * 4 + threadIdx.y;  // blockDim = (64,4): one wave per row
    if (r >= n) return;
    int f = threadIdx.x;
    int s0 = off[r], e1 = off[r + 1];
    float acc = 0.0f;
    for (int base = s0; base < e1; base += 64) {
        int idx = base + f;
        int myc = (idx < e1) ? csr[idx] : 0;
        int cnt = min(64, e1 - base);
        for (int t = 0; t < cnt; ++t) {
            int c = __shfl(myc, t);
            acc += y[(size_t)c * 64 + f];
        }
    }
    tx[(size_t)r * 64 + f] = -dis[r] * acc;
}

// ---------------- dense: out = act(h@W0 + tx@W1 + b); optionally y = dis*out ----------------

template <bool RELU, bool WRITE_Y>
__global__ __launch_bounds__(256) void dense64(const float* h_in,
                                               const float* __restrict__ tx,
                                               const float* __restrict__ W0,
                                               const float* __restrict__ W1,
                                               const float* __restrict__ bias,
                                               const float* __restrict__ dis,
                                               float* h_out,
                                               float* __restrict__ y, int n) {
    __shared__ float W0s[64 * 64];
    __shared__ float W1s[64 * 64];
    __shared__ float hs[16][68];
    __shared__ float ts[16][68];
    int tid = threadIdx.x;
    for (int idx = tid; idx < 4096; idx += 256) {
        W0s[idx] = W0[idx];
        W1s[idx] = W1[idx];
    }
    int row0 = blockIdx.x * 16;
    for (int idx = tid; idx < 1024; idx += 256) {
        int rr = idx >> 6, c = idx & 63;
        int r = row0 + rr;
        float hv = 0.f, tv = 0.f;
        if (r < n) {
            hv = h_in[(size_t)r * 64 + c];
            tv = tx[(size_t)r * 64 + c];
        }
        hs[rr][c] = hv;
        ts[rr][c] = tv;
    }
    __syncthreads();
    int jg = (tid & 15) * 4;  // column group
    int ty = tid >> 4;        // row within block (0..15)
    int r = row0 + ty;
    float a0 = bias[jg], a1 = bias[jg + 1], a2 = bias[jg + 2], a3 = bias[jg + 3];
#pragma unroll
    for (int k = 0; k < 64; ++k) {
        float hv = hs[ty][k], tv = ts[ty][k];
        float4 w0 = *(const float4*)&W0s[k * 64 + jg];
        float4 w1 = *(const float4*)&W1s[k * 64 + jg];
        a0 = fmaf(hv, w0.x, fmaf(tv, w1.x, a0));
        a1 = fmaf(hv, w0.y, fmaf(tv, w1.y, a1));
        a2 = fmaf(hv, w0.z, fmaf(tv, w1.z, a2));
        a3 = fmaf(hv, w0.w, fmaf(tv, w1.w, a3));
    }
    if (RELU) {
        a0 = fmaxf(a0, 0.f); a1 = fmaxf(a1, 0.f);
        a2 = fmaxf(a2, 0.f); a3 = fmaxf(a3, 0.f);
    }
    if (r < n) {
        float4 o = {a0, a1, a2, a3};
        *(float4*)&h_out[(size_t)r * 64 + jg] = o;
        if (WRITE_Y) {
            float dv = dis[r];
            float4 yv = {a0 * dv, a1 * dv, a2 * dv, a3 * dv};
            *(float4*)&y[(size_t)r * 64 + jg] = yv;
        }
    }
}

__global__ __launch_bounds__(256) void dense16(const float* __restrict__ h_in,
                                               const float* __restrict__ tx,
                                               const float* __restrict__ W0,
                                               const float* __restrict__ W1,
                                               const float* __restrict__ bias,
                                               float* __restrict__ out, int n) {
    __shared__ float W0s[64 * 16];
    __shared__ float W1s[64 * 16];
    __shared__ float hs[64][68];
    __shared__ float ts[64][68];
    int tid = threadIdx.x;
    for (int idx = tid; idx < 1024; idx += 256) {
        W0s[idx] = W0[idx];
        W1s[idx] = W1[idx];
    }
    int row0 = blockIdx.x * 64;
    for (int idx = tid; idx < 4096; idx += 256) {
        int rr = idx >> 6, c = idx & 63;
        int r = row0 + rr;
        float hv = 0.f, tv = 0.f;
        if (r < n) {
            hv = h_in[(size_t)r * 64 + c];
            tv = tx[(size_t)r * 64 + c];
        }
        hs[rr][c] = hv;
        ts[rr][c] = tv;
    }
    __syncthreads();
    int jg = (tid & 3) * 4;  // column group (16 cols -> 4 groups)
    int ty = tid >> 2;       // row within block (0..63)
    int r = row0 + ty;
    float a0 = bias[jg], a1 = bias[jg + 1], a2 = bias[jg + 2], a3 = bias[jg + 3];
#pragma unroll
    for (int k = 0; k < 64; ++k) {
        float hv = hs[ty][k], tv = ts[ty][k];
        float4 w0 = *(const float4*)&W0s[k * 16 + jg];
        float4 w1 = *(const float4*)&W1s[k * 16 + jg];
        a0 = fmaf(hv, w0.x, fmaf(tv, w1.x, a0));
        a1 = fmaf(hv, w0.y, fmaf(tv, w1.y, a1));
        a2 = fmaf(hv, w0.z, fmaf(tv, w1.z, a2));
        a3 = fmaf(hv, w0.w, fmaf(tv, w1.w, a3));
    }
    if (r < n) {
        float4 o = {a0, a1, a2, a3};
        *(float4*)&out[(size_t)r * 16 + jg] = o;
    }
}

// ---------------- launch ----------------

extern "C" void kernel_launch(void* const* d_in, const int* in_sizes, int n_in,
                              void* d_out, int out_size, void* d_ws, size_t ws_size,
                              hipStream_t stream) {
    const float* x    = (const float*)d_in[0];
    const int*   adj  = (const int*)d_in[1];
    const float* W1_0 = (const float*)d_in[2];
    const float* W1_1 = (const float*)d_in[3];
    const float* b1   = (const float*)d_in[4];
    const float* Wx_0 = (const float*)d_in[5];
    const float* Wx_1 = (const float*)d_in[6];
    const float* bx   = (const float*)d_in[7];
    const float* W2_0 = (const float*)d_in[8];
    const float* W2_1 = (const float*)d_in[9];
    const float* b2   = (const float*)d_in[10];
    float* out = (float*)d_out;

    int N = in_sizes[0] / 64;
    int E = in_sizes[1] / 2;
    const int* row = adj;
    const int* col = adj + E;

    char* p = (char*)d_ws;
    auto alloc = [&](size_t bytes) {
        char* q = p;
        p += (bytes + 255) & ~(size_t)255;
        return q;
    };
    int*   cnt  = (int*)alloc((size_t)N * 4);
    int*   off  = (int*)alloc((size_t)(N + 1) * 4);
    int*   bsum = (int*)alloc(1024 * 4);
    float* dis  = (float*)alloc((size_t)N * 4);
    int*   csr  = (int*)alloc((size_t)E * 4);
    float* y    = (float*)alloc((size_t)N * 64 * 4);
    float* tx   = (float*)alloc((size_t)N * 64 * 4);
    float* h    = (float*)alloc((size_t)N * 64 * 4);
    (void)ws_size;

    // CSR + normalization
    hipMemsetAsync(cnt, 0, (size_t)N * 4, stream);
    count_deg<<<(E + 255) / 256, 256, 0, stream>>>(row, cnt, E);
    int NB = (N + 1023) / 1024;
    scan1<<<NB, 1024, 0, stream>>>(cnt, off, bsum, N);
    scan2<<<1, 1024, 0, stream>>>(bsum, NB);
    scan3<<<(N + 255) / 256, 256, 0, stream>>>(off, bsum, N);
    compute_dis<<<(N + 255) / 256, 256, 0, stream>>>(cnt, dis, N);
    hipMemsetAsync(cnt, 0, (size_t)N * 4, stream);
    fill_csr<<<(E + 255) / 256, 256, 0, stream>>>(row, col, off, cnt, csr, E);

    dim3 ab(64, 4);
    // layer 1
    scale_y<<<(N * 16 + 255) / 256, 256, 0, stream>>>(x, dis, y, N);
    aggregate<<<(N + 3) / 4, ab, 0, stream>>>(y, csr, off, dis, tx, N);
    dense64<true, true><<<(N + 15) / 16, 256, 0, stream>>>(x, tx, W1_0, W1_1, b1, dis, h, y, N);
    // layer x
    aggregate<<<(N + 3) / 4, ab, 0, stream>>>(y, csr, off, dis, tx, N);
    dense64<true, true><<<(N + 15) / 16, 256, 0, stream>>>(h, tx, Wx_0, Wx_1, bx, dis, h, y, N);
    // layer 2
    aggregate<<<(N + 3) / 4, ab, 0, stream>>>(y, csr, off, dis, tx, N);
    dense16<<<(N + 63) / 64, 256, 0, stream>>>(h, tx, W2_0, W2_1, b2, out, N);
}